// Round 8
// baseline (449.507 us; speedup 1.0000x reference)
//
#include <hip/hip_runtime.h>
#include <hip/hip_bf16.h>

#define D_DIM 512
#define NROWS 256
#define NT 32
#define KSTEPS 16
#define GRID 256
#define S_SCALE 64.0f
#define COS_M 0.9210609940028851f
#define SIN_M 0.3894183423086505f

typedef short short8 __attribute__((ext_vector_type(8)));
typedef float f32x4 __attribute__((ext_vector_type(4)));

static __device__ __forceinline__ short f2bf(float f){
  __hip_bfloat16 h = __float2bfloat16(f);
  return __builtin_bit_cast(short, h);
}

// ---- emb = l2norm(x, 1e-5); also pack A-fragments (bf16, fragment-major) ----
__global__ void k_emb(const float* __restrict__ x, float* __restrict__ emb,
                      short* __restrict__ embA){
  int b = blockIdx.x, t = threadIdx.x;            // 256 blocks x 256 threads
  float v0 = x[b*D_DIM + t];
  float v1 = x[b*D_DIM + 256 + t];
  __shared__ float red[256];
  red[t] = v0*v0 + v1*v1;
  __syncthreads();
  for (int o=128;o>0;o>>=1){ if(t<o) red[t]+=red[t+o]; __syncthreads(); }
  float inv = 1.0f / fmaxf(sqrtf(red[0]), 1e-5f);
  float e0 = v0*inv, e1 = v1*inv;
  emb[b*D_DIM + t]       = e0;
  emb[b*D_DIM + 256 + t] = e1;
  int rb = b >> 4;
  {
    int d=t; int ks=d>>5, kg=(d>>3)&3, j=d&7;
    int lane=(kg<<4)|(b&15);
    embA[((ks*16+rb)*64+lane)*8+j] = f2bf(e0);
  }
  {
    int d=t+256; int ks=d>>5, kg=(d>>3)&3, j=d&7;
    int lane=(kg<<4)|(b&15);
    embA[((ks*16+rb)*64+lane)*8+j] = f2bf(e1);
  }
}

__global__ void k_init(int* __restrict__ upd, int C){
  int i = blockIdx.x*256 + threadIdx.x;
  if (i < C) upd[i] = -1;
}

// ---- virtual-prototype update ----
__global__ void k_vp(const float* __restrict__ queue, const float* __restrict__ emb,
                     const int* __restrict__ labels, float* __restrict__ newrow,
                     int* __restrict__ upd){
  int b = blockIdx.x, t = threadIdx.x;
  int lab = labels[b];
  const float* q = queue + (size_t)lab * D_DIM;
  float q0=q[t], q1=q[t+256];
  float e0=emb[b*D_DIM+t], e1=emb[b*D_DIM+256+t];
  __shared__ float red[256];
  __shared__ int win;
  red[t] = q0*e0 + q1*e1;
  __syncthreads();
  for (int o=128;o>0;o>>=1){ if(t<o) red[t]+=red[t+o]; __syncthreads(); }
  float drift = red[0];
  float fac = drift / (1.0f + fabsf(drift));
  float v0 = fac*q0 + (1.0f-fac)*e0;
  float v1 = fac*q1 + (1.0f-fac)*e1;
  __syncthreads();
  if (t==0) win = 1;
  red[t] = v0*v0 + v1*v1;
  __syncthreads();
  for (int o=128;o>0;o>>=1){ if(t<o) red[t]+=red[t+o]; __syncthreads(); }
  float inv = 1.0f / fmaxf(sqrtf(red[0]), 1e-12f);
  newrow[b*D_DIM+t]     = v0*inv;
  newrow[b*D_DIM+256+t] = v1*inv;
  if (t > b && labels[t] == lab) win = 0;
  __syncthreads();
  if (t==0 && win) upd[lab] = b;
}

// ---- fused double-GEMM: persistent, bf16-frag LDS, reg-resident A ----
// 256 blocks x 1024 thr (16 waves). Wave = mat (wave&1) x 2 rowblocks x 32 cls.
// Tile = 32 classes; LDS = 2 slots x (W 32KB + Q 32KB as bf16 frag-linear).
// Stage: whole 2KB rows -> regs (coalesced) -> f2bf once -> ds_write b128 at
// frag position; granule XOR key = ks&7 puts write AND read at the 8-lane/
// granule LDS minimum. Compute phase: 2 ds_read + 4 MFMA per ks, zero vmem.
// Norms computed stage-side in f32 (Gram MFMA deleted).
__global__ __launch_bounds__(1024,1) void k_main(
    const float* __restrict__ W, const float* __restrict__ Q,
    const short* __restrict__ embA, const float* __restrict__ newrow,
    const int* __restrict__ upd, const int* __restrict__ labels,
    float* __restrict__ partials, float* __restrict__ posval,
    int C, int ntiles)
{
  __shared__ __align__(16) char ldsb[2*65536];
  __shared__ float normlds[2][2][32];
  const int tid  = threadIdx.x;
  const int wave = tid >> 6;
  const int lane = tid & 63;
  const int lcol = lane & 15;
  const int lkg  = lane >> 4;
  const int smat = wave & 1;
  const int wrow = wave >> 1;                     // 0..7
  const int bid  = blockIdx.x;

  // A-fragment register cache: rowblocks wrow*2+{0,1}, all 16 ks (128 VGPR)
  const short8* Af = reinterpret_cast<const short8*>(embA);
  short8 afr[2][16];
#pragma unroll
  for (int ks=0;ks<16;ks++){
    afr[0][ks] = Af[(ks*16 + wrow*2 + 0)*64 + lane];
    afr[1][ks] = Af[(ks*16 + wrow*2 + 1)*64 + lane];
  }

  int labr[2][4];
#pragma unroll
  for (int rb=0;rb<2;rb++)
#pragma unroll
    for (int r=0;r<4;r++)
      labr[rb][r] = labels[wrow*32 + rb*16 + lkg*4 + r];

  // staging invariants (4 rows of matrix smat, cls_local = wrow*4+i)
  const int sks = lane >> 2;                      // frag ks of this lane's 8 elems
  const int swl = (lane & 3) * 16;                // frag-lane high part
  f32x4 ldv[8];
  int updv[4] = {-1,-1,-1,-1};

  auto UPD = [&](int T){
    if (smat && T < ntiles){
#pragma unroll
      for (int i=0;i<4;i++) updv[i] = upd[T*NT + wrow*4 + i];
    }
  };
  auto ISSUE = [&](int T){
#pragma unroll
    for (int i=0;i<4;i++){
      int cls = T*NT + wrow*4 + i;
      const float* p;
      if (smat) p = (updv[i] >= 0) ? (newrow + (size_t)updv[i]*D_DIM)
                                   : (Q + (size_t)cls*D_DIM);
      else      p = W + (size_t)cls*D_DIM;
      ldv[2*i]   = *(const f32x4*)(p + lane*8);
      ldv[2*i+1] = *(const f32x4*)(p + lane*8 + 4);
    }
    __builtin_amdgcn_sched_barrier(0);
  };
  auto WRITE = [&](int par){
#pragma unroll
    for (int i=0;i<4;i++){
      int cl = wrow*4 + i;
      f32x4 a = ldv[2*i], b = ldv[2*i+1];
      float ss = a[0]*a[0]+a[1]*a[1]+a[2]*a[2]+a[3]*a[3]
               + b[0]*b[0]+b[1]*b[1]+b[2]*b[2]+b[3]*b[3];
      ss += __shfl_xor(ss, 1);  ss += __shfl_xor(ss, 2);
      ss += __shfl_xor(ss, 4);  ss += __shfl_xor(ss, 8);
      ss += __shfl_xor(ss, 16); ss += __shfl_xor(ss, 32);
      if (lane == 0) normlds[par][smat][cl] = ss;
      short8 v;
#pragma unroll
      for (int j=0;j<4;j++){ v[j] = f2bf(a[j]); v[4+j] = f2bf(b[j]); }
      int lam  = swl + (cl & 15);
      int addr = par*65536 + smat*32768 + ((cl>>4)*16 + sks)*1024
               + ((lam ^ (sks & 7)) << 4);
      *(short8*)(ldsb + addr) = v;                // ds_write_b128
    }
  };

  const f32x4 vzero = {0.f,0.f,0.f,0.f};
  f32x4 acc[2][2];                                // [rowblock][colblock]
  acc[0][0]=vzero; acc[0][1]=vzero; acc[1][0]=vzero; acc[1][1]=vzero;

  // prologue: tile t0 staged+written to slot0; t0+G in flight; upd(t0+2G) held
  const int t0 = bid;
  UPD(t0);
  ISSUE(t0);
  WRITE(0);
  UPD(t0 + GRID);
  if (t0 + GRID < ntiles) ISSUE(t0 + GRID);
  UPD(t0 + 2*GRID);
  __syncthreads();

  int par = 0;
  for (int t = t0; t < ntiles; t += GRID, par ^= 1){
    // ---- compute: 16 ks of {2 ds_read_b128, 4 MFMA}, zero vmem ----
    const char* base = ldsb + par*65536 + smat*32768;
#pragma unroll
    for (int ks=0; ks<KSTEPS; ++ks){
      const int ro = ((lane ^ (ks & 7)) << 4);
      const short8 b0 = *(const short8*)(base + ks*1024        + ro);
      const short8 b1 = *(const short8*)(base + (16+ks)*1024   + ro);
      acc[0][0] = __builtin_amdgcn_mfma_f32_16x16x32_bf16(afr[0][ks], b0, acc[0][0], 0, 0, 0);
      acc[1][0] = __builtin_amdgcn_mfma_f32_16x16x32_bf16(afr[1][ks], b0, acc[1][0], 0, 0, 0);
      acc[0][1] = __builtin_amdgcn_mfma_f32_16x16x32_bf16(afr[0][ks], b1, acc[0][1], 0, 0, 0);
      acc[1][1] = __builtin_amdgcn_mfma_f32_16x16x32_bf16(afr[1][ks], b1, acc[1][1], 0, 0, 0);
    }

    // ---- epilogue (runs while HBM tail of next-tile loads drains) ----
    float ninv[2];
#pragma unroll
    for (int cb=0;cb<2;cb++){
      float ss = normlds[par][smat][cb*16 + lcol];
      ninv[cb] = 1.0f / fmaxf(sqrtf(ss), smat ? 1e-12f : 1e-5f);
    }
#pragma unroll
    for (int rb=0;rb<2;rb++){
#pragma unroll
      for (int r=0;r<4;r++){
        const int m   = wrow*32 + rb*16 + lkg*4 + r;
        const int lab = labr[rb][r];
        float nn = 0.f;
#pragma unroll
        for (int cb=0;cb<2;cb++){
          const int c = t*NT + cb*16 + lcol;
          float v = acc[rb][cb][r] * ninv[cb];
          if (!smat){
            v = fminf(fmaxf(v, -1.0f + 1e-7f), 1.0f - 1e-7f);
            if (c == lab){
              float s  = sqrtf(fminf(fmaxf(1.0f - v*v, 0.0f), 1.0f));
              posval[m] = __expf(-S_SCALE*(v*COS_M - s*SIN_M));
            } else nn += __expf(S_SCALE*v);
          } else {
            if (c == lab){
              float vq = 0.3f * v;
              float s  = sqrtf(fminf(fmaxf(1.0f - vq*vq, 0.0f), 1.0f));
              posval[NROWS + m] = __expf(-S_SCALE*(vq*COS_M - s*SIN_M));
            } else nn += __expf(S_SCALE*v);
          }
        }
#pragma unroll
        for (int msk=1; msk<16; msk<<=1) nn += __shfl_xor(nn, msk);
        if (lcol == 0)
          partials[(size_t)t*512 + smat*256 + m] = nn;
      }
    }
    acc[0][0]=vzero; acc[0][1]=vzero; acc[1][0]=vzero; acc[1][1]=vzero;

    // ---- stage next: write t+G (vmcnt via data dep), issue t+2G ----
    if (t + GRID < ntiles)   WRITE(par ^ 1);
    if (t + 2*GRID < ntiles){ ISSUE(t + 2*GRID); UPD(t + 3*GRID); }
    __syncthreads();
  }
}

// ---- reduce partials per row (coalesced 16-column tiles), loss per row ----
__global__ void k_red(const float* __restrict__ partials, const float* __restrict__ posval,
                      float* __restrict__ lossv, int nwg){
  int n0 = blockIdx.x * 16;                       // 32 blocks x 256 threads
  int tx = threadIdx.x & 15, ty = threadIdx.x >> 4;
  float s = 0.f;
  for (int i=ty; i<nwg; i+=16) s += partials[(size_t)i*512 + n0 + tx];
  __shared__ float red[16][17];
  red[ty][tx] = s;
  __syncthreads();
  if (ty == 0){
    float acc = 0.f;
#pragma unroll
    for (int j=0;j<16;j++) acc += red[j][tx];
    int n = n0 + tx;
    lossv[n] = logf(1.0f + acc * posval[n]);
  }
}

__global__ void k_fin(const float* __restrict__ lossv, const int* __restrict__ epoch,
                      float* __restrict__ out){
  int t = threadIdx.x;
  int N = (epoch[0] + 1 >= 4) ? 2*NROWS : NROWS;
  float v = (t < N) ? lossv[t] : 0.f;
  __shared__ float red[512];
  red[t] = v; __syncthreads();
  for (int o=256;o>0;o>>=1){ if(t<o) red[t]+=red[t+o]; __syncthreads(); }
  if (t==0) out[0] = red[0] / (float)N;
}

extern "C" void kernel_launch(void* const* d_in, const int* in_sizes, int n_in,
                              void* d_out, int out_size, void* d_ws, size_t ws_size,
                              hipStream_t stream)
{
  const float* x      = (const float*)d_in[0];
  const int*   labels = (const int*)d_in[1];
  const float* W      = (const float*)d_in[2];
  const float* Q      = (const float*)d_in[3];
  const int*   epoch  = (const int*)d_in[4];
  float* out = (float*)d_out;
  const int C      = in_sizes[2] / D_DIM;         // 100000
  const int ntiles = (C + NT - 1) / NT;           // 3125 (exact: 3125*32)

  char* ws = (char*)d_ws;
  float* emb      = (float*)(ws + 0);             // 512 KB
  short* embA     = (short*)(ws + 524288);        // 256 KB
  float* newrow   = (float*)(ws + 786432);        // 512 KB
  int*   upd      = (int*)  (ws + 1310720);       // 400 KB
  float* posval   = (float*)(ws + 1712128);       // 2 KB
  float* lossv    = (float*)(ws + 1714176);       // 2 KB
  float* partials = (float*)(ws + 1716224);       // 512*ntiles*4 B (~6.4 MB)

  hipLaunchKernelGGL(k_emb,  dim3(NROWS),       dim3(256),  0, stream, x, emb, embA);
  hipLaunchKernelGGL(k_init, dim3((C+255)/256), dim3(256),  0, stream, upd, C);
  hipLaunchKernelGGL(k_vp,   dim3(NROWS),       dim3(256),  0, stream, Q, emb, labels, newrow, upd);
  hipLaunchKernelGGL(k_main, dim3(GRID),        dim3(1024), 0, stream,
                     W, Q, embA, newrow, upd, labels, partials, posval, C, ntiles);
  hipLaunchKernelGGL(k_red,  dim3(32),          dim3(256),  0, stream, partials, posval, lossv, ntiles);
  hipLaunchKernelGGL(k_fin,  dim3(1),           dim3(512),  0, stream, lossv, epoch, out);
}

// Round 9
// 349.968 us; speedup vs baseline: 1.2844x; 1.2844x over previous
//
#include <hip/hip_runtime.h>
#include <hip/hip_bf16.h>

#define D_DIM 512
#define NROWS 256
#define NT 16
#define KSTEPS 16
#define GRIDP 512
#define S_SCALE 64.0f
#define COS_M 0.9210609940028851f
#define SIN_M 0.3894183423086505f

typedef short short8 __attribute__((ext_vector_type(8)));
typedef float f32x4 __attribute__((ext_vector_type(4)));

typedef const __attribute__((address_space(1))) void* gas1_t;
typedef __attribute__((address_space(3))) void* las3_t;

static __device__ __forceinline__ void gload16(const void* g, void* l){
  __builtin_amdgcn_global_load_lds((gas1_t)g, (las3_t)l, 16, 0, 0);
}

static __device__ __forceinline__ short f2bf(float f){
  __hip_bfloat16 h = __float2bfloat16(f);
  return __builtin_bit_cast(short, h);
}

// ---- emb = l2norm(x, 1e-5); pack A-fragments; also init upd[] ----
__global__ void k_emb(const float* __restrict__ x, float* __restrict__ emb,
                      short* __restrict__ embA, int* __restrict__ upd, int C){
  int b = blockIdx.x, t = threadIdx.x;            // 256 blocks x 256 threads
  {
    int id = b*256 + t;
    if (id < C)         upd[id] = -1;
    if (id + 65536 < C) upd[id + 65536] = -1;
  }
  float v0 = x[b*D_DIM + t];
  float v1 = x[b*D_DIM + 256 + t];
  __shared__ float red[256];
  red[t] = v0*v0 + v1*v1;
  __syncthreads();
  for (int o=128;o>0;o>>=1){ if(t<o) red[t]+=red[t+o]; __syncthreads(); }
  float inv = 1.0f / fmaxf(sqrtf(red[0]), 1e-5f);
  float e0 = v0*inv, e1 = v1*inv;
  emb[b*D_DIM + t]       = e0;
  emb[b*D_DIM + 256 + t] = e1;
  int rb = b >> 4;
  {
    int d=t; int ks=d>>5, kg=(d>>3)&3, j=d&7;
    int lane=(kg<<4)|(b&15);
    embA[((ks*16+rb)*64+lane)*8+j] = f2bf(e0);
  }
  {
    int d=t+256; int ks=d>>5, kg=(d>>3)&3, j=d&7;
    int lane=(kg<<4)|(b&15);
    embA[((ks*16+rb)*64+lane)*8+j] = f2bf(e1);
  }
}

// ---- virtual-prototype update ----
__global__ void k_vp(const float* __restrict__ queue, const float* __restrict__ emb,
                     const int* __restrict__ labels, float* __restrict__ newrow,
                     int* __restrict__ upd){
  int b = blockIdx.x, t = threadIdx.x;
  int lab = labels[b];
  const float* q = queue + (size_t)lab * D_DIM;
  float q0=q[t], q1=q[t+256];
  float e0=emb[b*D_DIM+t], e1=emb[b*D_DIM+256+t];
  __shared__ float red[256];
  __shared__ int win;
  red[t] = q0*e0 + q1*e1;
  __syncthreads();
  for (int o=128;o>0;o>>=1){ if(t<o) red[t]+=red[t+o]; __syncthreads(); }
  float drift = red[0];
  float fac = drift / (1.0f + fabsf(drift));
  float v0 = fac*q0 + (1.0f-fac)*e0;
  float v1 = fac*q1 + (1.0f-fac)*e1;
  __syncthreads();
  if (t==0) win = 1;
  red[t] = v0*v0 + v1*v1;
  __syncthreads();
  for (int o=128;o>0;o>>=1){ if(t<o) red[t]+=red[t+o]; __syncthreads(); }
  float inv = 1.0f / fmaxf(sqrtf(red[0]), 1e-12f);
  newrow[b*D_DIM+t]     = v0*inv;
  newrow[b*D_DIM+256+t] = v1*inv;
  if (t > b && labels[t] == lab) win = 0;
  __syncthreads();
  if (t==0 && win) upd[lab] = b;
}

// ---- fused double-GEMM: persistent ping-pong whole-row streamer ----
// 512 blocks (2/CU), 512 threads (8 waves). LDS = 2 slots x 32KB.
// Tile = 16 classes. Per tile: sync; issue Q(t)->slot1; compute W(slot0);
// sync; issue W(t+GRIDP)->slot0; compute Q(slot1); epilogue. With 2 blocks/CU
// the partner block's MFMA/loads cover this block's barrier drain + epilogue.
__global__ __launch_bounds__(512,4) void k_main(
    const float* __restrict__ W, const float* __restrict__ Q,
    const short* __restrict__ embA, const float* __restrict__ newrow,
    const int* __restrict__ upd, const int* __restrict__ labels,
    float* __restrict__ partials, float* __restrict__ posval,
    int C, int ntiles)
{
  __shared__ __align__(16) char ldsb[65536];      // [2 slots][16 rows][2048]
  const int bid  = blockIdx.x;
  const int tid  = threadIdx.x;
  const int wave = tid >> 6;                      // 0..7
  const int lane = tid & 63;
  const int lcol = lane & 15;
  const int lkg  = lane >> 4;

  // staging: wave stages rows r0=wave*2, r1=wave*2+1 of each matrix (2KB rows)
  const int r0 = wave*2, r1 = wave*2 + 1;
  const int sw0 = ((lane ^ (r0 & 7)) << 4);       // pre-swizzled source offset
  const int sw1 = ((lane ^ (r1 & 7)) << 4);

  // hoisted labels for this wave's 32 rows
  int labr[2][4];
#pragma unroll
  for (int rb=0;rb<2;rb++)
#pragma unroll
    for (int r=0;r<4;r++)
      labr[rb][r] = labels[wave*32 + rb*16 + lkg*4 + r];

  const short8* Af = reinterpret_cast<const short8*>(embA);
  // ds_read bases: addr = lcol*2048 + (ks*8 + ((lkg*2)^key))*16, key=lcol&7
  const int key  = lcol & 7;
  const int dsb0 = lcol*2048 + (((lkg*2) ^ key) << 4);
  const int dsb1 = dsb0 ^ 16;

  const f32x4 vzero = {0.f,0.f,0.f,0.f};
  f32x4 accW[2], accQ[2], accNW, accNQ;
  accW[0]=vzero; accW[1]=vzero; accQ[0]=vzero; accQ[1]=vzero;
  accNW=vzero; accNQ=vzero;

  // A-frag register cache, loaded once (tile-invariant)
  short8 afr[2][16];
#pragma unroll
  for (int ks=0;ks<16;ks++){
    afr[0][ks] = Af[(ks*16 + wave*2 + 0)*64 + lane];
    afr[1][ks] = Af[(ks*16 + wave*2 + 1)*64 + lane];
  }

  int t = bid;
  // prologue: upd for tile t; stage W(t) -> slot0
  int updc0 = upd[t*16 + r0];
  int updc1 = upd[t*16 + r1];
  {
    const char* w0p = (const char*)(W + (size_t)(t*16 + r0) * D_DIM);
    const char* w1p = (const char*)(W + (size_t)(t*16 + r1) * D_DIM);
    gload16(w0p + sw0,        ldsb + r0*2048);
    gload16(w0p + 1024 + sw0, ldsb + r0*2048 + 1024);
    gload16(w1p + sw1,        ldsb + r1*2048);
    gload16(w1p + 1024 + sw1, ldsb + r1*2048 + 1024);
  }

  for (; t < ntiles; t += GRIDP){
    const int tn = t + GRIDP;
    // ================= W-slot =================
    __syncthreads();                              // W(t) ready in slot0
    // issue Q(t) stage -> slot1 (in flight during W-compute)
    {
      const float* q0p = (updc0 >= 0) ? (newrow + (size_t)updc0 * D_DIM)
                                      : (Q + (size_t)(t*16 + r0) * D_DIM);
      const float* q1p = (updc1 >= 0) ? (newrow + (size_t)updc1 * D_DIM)
                                      : (Q + (size_t)(t*16 + r1) * D_DIM);
      gload16((const char*)q0p + sw0,        ldsb + 32768 + r0*2048);
      gload16((const char*)q0p + 1024 + sw0, ldsb + 32768 + r0*2048 + 1024);
      gload16((const char*)q1p + sw1,        ldsb + 32768 + r1*2048);
      gload16((const char*)q1p + 1024 + sw1, ldsb + 32768 + r1*2048 + 1024);
    }
    __builtin_amdgcn_sched_barrier(0);
    // prefetch upd for next tile
    int updn0 = -1, updn1 = -1;
    if (tn < ntiles){ updn0 = upd[tn*16 + r0]; updn1 = upd[tn*16 + r1]; }

    __builtin_amdgcn_s_setprio(1);
#pragma unroll
    for (int ks=0; ks<KSTEPS; ++ks){
      const f32x4 w0 = *(const f32x4*)(ldsb + dsb0 + ks*128);
      const f32x4 w1 = *(const f32x4*)(ldsb + dsb1 + ks*128);
      short8 bw;
#pragma unroll
      for (int j=0;j<4;j++){ bw[j] = f2bf(w0[j]); bw[j+4] = f2bf(w1[j]); }
      accNW   = __builtin_amdgcn_mfma_f32_16x16x32_bf16(bw, bw, accNW, 0, 0, 0);
      accW[0] = __builtin_amdgcn_mfma_f32_16x16x32_bf16(afr[0][ks], bw, accW[0], 0, 0, 0);
      accW[1] = __builtin_amdgcn_mfma_f32_16x16x32_bf16(afr[1][ks], bw, accW[1], 0, 0, 0);
    }
    __builtin_amdgcn_s_setprio(0);

    // ================= Q-slot =================
    __syncthreads();                              // Q(t) ready in slot1
    if (tn < ntiles){                             // issue W(tn) -> slot0
      const char* w0p = (const char*)(W + (size_t)(tn*16 + r0) * D_DIM);
      const char* w1p = (const char*)(W + (size_t)(tn*16 + r1) * D_DIM);
      gload16(w0p + sw0,        ldsb + r0*2048);
      gload16(w0p + 1024 + sw0, ldsb + r0*2048 + 1024);
      gload16(w1p + sw1,        ldsb + r1*2048);
      gload16(w1p + 1024 + sw1, ldsb + r1*2048 + 1024);
    }
    __builtin_amdgcn_sched_barrier(0);

    __builtin_amdgcn_s_setprio(1);
#pragma unroll
    for (int ks=0; ks<KSTEPS; ++ks){
      const f32x4 z0 = *(const f32x4*)(ldsb + 32768 + dsb0 + ks*128);
      const f32x4 z1 = *(const f32x4*)(ldsb + 32768 + dsb1 + ks*128);
      short8 bq;
#pragma unroll
      for (int j=0;j<4;j++){ bq[j] = f2bf(z0[j]); bq[j+4] = f2bf(z1[j]); }
      accNQ   = __builtin_amdgcn_mfma_f32_16x16x32_bf16(bq, bq, accNQ, 0, 0, 0);
      accQ[0] = __builtin_amdgcn_mfma_f32_16x16x32_bf16(afr[0][ks], bq, accQ[0], 0, 0, 0);
      accQ[1] = __builtin_amdgcn_mfma_f32_16x16x32_bf16(afr[1][ks], bq, accQ[1], 0, 0, 0);
    }
    __builtin_amdgcn_s_setprio(0);

    // ================= epilogue (tile t) =================
    float winv, qinv;
    {
      int rsel = lcol & 3;
      float vw = rsel==0?accNW[0]:rsel==1?accNW[1]:rsel==2?accNW[2]:accNW[3];
      float vq = rsel==0?accNQ[0]:rsel==1?accNQ[1]:rsel==2?accNQ[2]:accNQ[3];
      int src = ((lcol>>2)<<4) | lcol;            // diag col c on lane ((c>>2)<<4)|c
      float ssW = __shfl(vw, src);
      float ssQ = __shfl(vq, src);
      winv = 1.0f / fmaxf(sqrtf(ssW), 1e-5f);
      qinv = 1.0f / fmaxf(sqrtf(ssQ), 1e-12f);
    }
    const int c = t*16 + lcol;
#pragma unroll
    for (int rb=0;rb<2;rb++){
#pragma unroll
      for (int r=0;r<4;r++){
        const int m = wave*32 + rb*16 + lkg*4 + r;
        const int lab = labr[rb][r];
        float nw = 0.f, nq = 0.f;
        {
          float cw = accW[rb][r] * winv;
          cw = fminf(fmaxf(cw, -1.0f + 1e-7f), 1.0f - 1e-7f);
          float cq = accQ[rb][r] * qinv;
          if (c == lab){
            float sw  = sqrtf(fminf(fmaxf(1.0f - cw*cw, 0.0f), 1.0f));
            float phw = cw*COS_M - sw*SIN_M;
            posval[m] = __expf(-S_SCALE*phw);
            float vq  = 0.3f * cq;
            float sq  = sqrtf(fminf(fmaxf(1.0f - vq*vq, 0.0f), 1.0f));
            float phq = vq*COS_M - sq*SIN_M;
            posval[NROWS + m] = __expf(-S_SCALE*phq);
          } else {
            nw = __expf(S_SCALE*cw);
            nq = __expf(S_SCALE*cq);
          }
        }
#pragma unroll
        for (int msk=1; msk<16; msk<<=1){
          nw += __shfl_xor(nw, msk);
          nq += __shfl_xor(nq, msk);
        }
        if (lcol == 0){
          partials[(size_t)t*512 + m]       = nw;
          partials[(size_t)t*512 + 256 + m] = nq;
        }
      }
    }
    // rotate state
    updc0 = updn0; updc1 = updn1;
    accW[0]=vzero; accW[1]=vzero; accQ[0]=vzero; accQ[1]=vzero;
    accNW=vzero; accNQ=vzero;
  }
}

// ---- reduce partials per row (R3 envelope: 512 blocks), loss per row ----
__global__ void k_red(const float* __restrict__ partials, const float* __restrict__ posval,
                      float* __restrict__ lossv, int nwg){
  int n = blockIdx.x, t = threadIdx.x;            // 512 blocks x 256 threads
  float s = 0.f;
  for (int i=t; i<nwg; i+=256) s += partials[(size_t)i*512 + n];
  __shared__ float red[256];
  red[t] = s; __syncthreads();
  for (int o=128;o>0;o>>=1){ if(t<o) red[t]+=red[t+o]; __syncthreads(); }
  if (t==0) lossv[n] = logf(1.0f + red[0] * posval[n]);
}

__global__ void k_fin(const float* __restrict__ lossv, const int* __restrict__ epoch,
                      float* __restrict__ out){
  int t = threadIdx.x;
  int N = (epoch[0] + 1 >= 4) ? 2*NROWS : NROWS;
  float v = (t < N) ? lossv[t] : 0.f;
  __shared__ float red[512];
  red[t] = v; __syncthreads();
  for (int o=256;o>0;o>>=1){ if(t<o) red[t]+=red[t+o]; __syncthreads(); }
  if (t==0) out[0] = red[0] / (float)N;
}

extern "C" void kernel_launch(void* const* d_in, const int* in_sizes, int n_in,
                              void* d_out, int out_size, void* d_ws, size_t ws_size,
                              hipStream_t stream)
{
  const float* x      = (const float*)d_in[0];
  const int*   labels = (const int*)d_in[1];
  const float* W      = (const float*)d_in[2];
  const float* Q      = (const float*)d_in[3];
  const int*   epoch  = (const int*)d_in[4];
  float* out = (float*)d_out;
  const int C      = in_sizes[2] / D_DIM;         // 100000
  const int ntiles = (C + NT - 1) / NT;           // 6250

  char* ws = (char*)d_ws;
  float* emb      = (float*)(ws + 0);             // 512 KB
  short* embA     = (short*)(ws + 524288);        // 256 KB
  float* newrow   = (float*)(ws + 786432);        // 512 KB
  int*   upd      = (int*)  (ws + 1310720);       // 400 KB
  float* posval   = (float*)(ws + 1712128);       // 2 KB
  float* lossv    = (float*)(ws + 1714176);       // 2 KB
  float* partials = (float*)(ws + 1716224);       // 512*ntiles*4 B (~12.8 MB)

  hipLaunchKernelGGL(k_emb,  dim3(NROWS),  dim3(256), 0, stream, x, emb, embA, upd, C);
  hipLaunchKernelGGL(k_vp,   dim3(NROWS),  dim3(256), 0, stream, Q, emb, labels, newrow, upd);
  hipLaunchKernelGGL(k_main, dim3(GRIDP),  dim3(512), 0, stream,
                     W, Q, embA, newrow, upd, labels, partials, posval, C, ntiles);
  hipLaunchKernelGGL(k_red,  dim3(2*NROWS),dim3(256), 0, stream, partials, posval, lossv, ntiles);
  hipLaunchKernelGGL(k_fin,  dim3(1),      dim3(512), 0, stream, lossv, epoch, out);
}

// Round 10
// 217.877 us; speedup vs baseline: 2.0631x; 1.6063x over previous
//
#include <hip/hip_runtime.h>
#include <hip/hip_bf16.h>

#define D_DIM 512
#define NROWS 256
#define NT 16
#define KSTEPS 16
#define GRID 256
#define S_SCALE 64.0f
#define COS_M 0.9210609940028851f
#define SIN_M 0.3894183423086505f

typedef short short8 __attribute__((ext_vector_type(8)));
typedef float f32x4 __attribute__((ext_vector_type(4)));

typedef const __attribute__((address_space(1))) void* gas1_t;
typedef __attribute__((address_space(3))) void* las3_t;

static __device__ __forceinline__ void gload16(const void* g, void* l){
  __builtin_amdgcn_global_load_lds((gas1_t)g, (las3_t)l, 16, 0, 0);
}

static __device__ __forceinline__ short f2bf(float f){
  __hip_bfloat16 h = __float2bfloat16(f);
  return __builtin_bit_cast(short, h);
}

// ---- emb = l2norm(x, 1e-5); pack A-fragments; also init upd[] ----
__global__ void k_emb(const float* __restrict__ x, float* __restrict__ emb,
                      short* __restrict__ embA, int* __restrict__ upd, int C){
  int b = blockIdx.x, t = threadIdx.x;            // 256 blocks x 256 threads
  {
    int id = b*256 + t;
    if (id < C)         upd[id] = -1;
    if (id + 65536 < C) upd[id + 65536] = -1;
  }
  float v0 = x[b*D_DIM + t];
  float v1 = x[b*D_DIM + 256 + t];
  __shared__ float red[256];
  red[t] = v0*v0 + v1*v1;
  __syncthreads();
  for (int o=128;o>0;o>>=1){ if(t<o) red[t]+=red[t+o]; __syncthreads(); }
  float inv = 1.0f / fmaxf(sqrtf(red[0]), 1e-5f);
  float e0 = v0*inv, e1 = v1*inv;
  emb[b*D_DIM + t]       = e0;
  emb[b*D_DIM + 256 + t] = e1;
  int rb = b >> 4;
  {
    int d=t; int ks=d>>5, kg=(d>>3)&3, j=d&7;
    int lane=(kg<<4)|(b&15);
    embA[((ks*16+rb)*64+lane)*8+j] = f2bf(e0);
  }
  {
    int d=t+256; int ks=d>>5, kg=(d>>3)&3, j=d&7;
    int lane=(kg<<4)|(b&15);
    embA[((ks*16+rb)*64+lane)*8+j] = f2bf(e1);
  }
}

// ---- virtual-prototype update ----
__global__ void k_vp(const float* __restrict__ queue, const float* __restrict__ emb,
                     const int* __restrict__ labels, float* __restrict__ newrow,
                     int* __restrict__ upd){
  int b = blockIdx.x, t = threadIdx.x;
  int lab = labels[b];
  const float* q = queue + (size_t)lab * D_DIM;
  float q0=q[t], q1=q[t+256];
  float e0=emb[b*D_DIM+t], e1=emb[b*D_DIM+256+t];
  __shared__ float red[256];
  __shared__ int win;
  red[t] = q0*e0 + q1*e1;
  __syncthreads();
  for (int o=128;o>0;o>>=1){ if(t<o) red[t]+=red[t+o]; __syncthreads(); }
  float drift = red[0];
  float fac = drift / (1.0f + fabsf(drift));
  float v0 = fac*q0 + (1.0f-fac)*e0;
  float v1 = fac*q1 + (1.0f-fac)*e1;
  __syncthreads();
  if (t==0) win = 1;
  red[t] = v0*v0 + v1*v1;
  __syncthreads();
  for (int o=128;o>0;o>>=1){ if(t<o) red[t]+=red[t+o]; __syncthreads(); }
  float inv = 1.0f / fmaxf(sqrtf(red[0]), 1e-12f);
  newrow[b*D_DIM+t]     = v0*inv;
  newrow[b*D_DIM+256+t] = v1*inv;
  if (t > b && labels[t] == lab) win = 0;
  __syncthreads();
  if (t==0 && win) upd[lab] = b;
}

// ---- fused double-GEMM: persistent 4-slot ring, counted vmcnt, zero-vmem loop ----
// 256 blocks (1/CU) x 512 thr (8 waves). Ring: 4 slots x 32KB; slot j holds
// half-tile j (mat=j&1, tile k=j>>1, t=bid+k*GRID). Steady state: wait
// vmcnt(8) retires stage j exactly, leaves stages j+1,j+2 (64KB/CU) in
// flight ACROSS the barrier; stage j+3 issued right after. Compute phase has
// ZERO vmem: afr hoisted (128 VGPR), upd in LDS, labels hoisted, epilogue
// accumulated in registers and flushed once at kernel end.
__global__ __launch_bounds__(512,2) void k_main(
    const float* __restrict__ W, const float* __restrict__ Q,
    const short* __restrict__ embA, const float* __restrict__ newrow,
    const int* __restrict__ upd, const int* __restrict__ labels,
    float* __restrict__ partials, float* __restrict__ posval,
    int C, int ntiles)
{
  __shared__ __align__(16) char ldsb[131072];     // 4 slots x [16 rows][2048]
  __shared__ int upd_lds[25*16];
  const int bid  = blockIdx.x;
  const int tid  = threadIdx.x;
  const int wave = tid >> 6;                      // 0..7
  const int lane = tid & 63;
  const int lcol = lane & 15;
  const int lkg  = lane >> 4;
  const int r0 = wave*2, r1 = wave*2 + 1;
  const int sw0 = ((lane ^ (r0 & 7)) << 4);       // pre-swizzled source offset
  const int sw1 = ((lane ^ (r1 & 7)) << 4);
  const int ntb  = (ntiles - bid + GRID - 1) / GRID;
  const int jmax = 2*ntb;

  // upd for all this block's tiles -> LDS (keeps loop vmem-free)
  for (int i = tid; i < ntb*16; i += 512)
    upd_lds[i] = upd[(bid + (i>>4)*GRID)*16 + (i&15)];
  __syncthreads();

  // hoisted labels + A-frag register cache (BEFORE stages in vm FIFO)
  int labr[2][4];
#pragma unroll
  for (int rb=0;rb<2;rb++)
#pragma unroll
    for (int r=0;r<4;r++)
      labr[rb][r] = labels[wave*32 + rb*16 + lkg*4 + r];
  const short8* Af = reinterpret_cast<const short8*>(embA);
  short8 afr[2][16];
#pragma unroll
  for (int ks=0;ks<16;ks++){
    afr[0][ks] = Af[(ks*16 + wave*2 + 0)*64 + lane];
    afr[1][ks] = Af[(ks*16 + wave*2 + 1)*64 + lane];
  }
  __builtin_amdgcn_sched_barrier(0);

  auto ISSUE = [&](int jj){
    const int mat = jj & 1, k = jj >> 1;
    const int t   = bid + k*GRID;
    const char *p0, *p1;
    if (mat == 0){
      p0 = (const char*)(W + (size_t)(t*16 + r0) * D_DIM);
      p1 = (const char*)(W + (size_t)(t*16 + r1) * D_DIM);
    } else {
      int u0 = upd_lds[k*16 + r0];
      int u1 = upd_lds[k*16 + r1];
      p0 = (const char*)(u0 >= 0 ? newrow + (size_t)u0*D_DIM
                                 : Q + (size_t)(t*16 + r0)*D_DIM);
      p1 = (const char*)(u1 >= 0 ? newrow + (size_t)u1*D_DIM
                                 : Q + (size_t)(t*16 + r1)*D_DIM);
    }
    char* db = ldsb + (jj & 3)*32768;
    gload16(p0 + sw0,        db + r0*2048);
    gload16(p0 + 1024 + sw0, db + r0*2048 + 1024);
    gload16(p1 + sw1,        db + r1*2048);
    gload16(p1 + 1024 + sw1, db + r1*2048 + 1024);
  };

  // prologue: 3 slots in flight
  ISSUE(0);
  if (1 < jmax) ISSUE(1);
  if (2 < jmax) ISSUE(2);
  __builtin_amdgcn_sched_barrier(0);

  const int key  = lcol & 7;
  const int dsro = lcol*2048 + (((lkg*2) ^ key) << 4);

  const f32x4 vzero = {0.f,0.f,0.f,0.f};
  f32x4 accW[2], accQ[2], accNW, accNQ;
  accW[0]=vzero; accW[1]=vzero; accQ[0]=vzero; accQ[1]=vzero;
  accNW=vzero; accNQ=vzero;
  float nwacc[2][4] = {{0.f,0.f,0.f,0.f},{0.f,0.f,0.f,0.f}};
  float nqacc[2][4] = {{0.f,0.f,0.f,0.f},{0.f,0.f,0.f,0.f}};
  float posW[2][4]  = {{-1.f,-1.f,-1.f,-1.f},{-1.f,-1.f,-1.f,-1.f}};
  float posQ[2][4]  = {{-1.f,-1.f,-1.f,-1.f},{-1.f,-1.f,-1.f,-1.f}};

  for (int j = 0; j < jmax; ++j){
    if (j + 2 < jmax)      asm volatile("s_waitcnt vmcnt(8)" ::: "memory");
    else if (j + 1 < jmax) asm volatile("s_waitcnt vmcnt(4)" ::: "memory");
    else                   asm volatile("s_waitcnt vmcnt(0)" ::: "memory");
    __builtin_amdgcn_s_barrier();
    __builtin_amdgcn_sched_barrier(0);
    if (j + 3 < jmax) ISSUE(j + 3);
    __builtin_amdgcn_sched_barrier(0);

    const char* bb = ldsb + (j & 3)*32768;
    if ((j & 1) == 0){
      // ---- W half-tile: pure LDS + MFMA ----
#pragma unroll
      for (int ks=0; ks<KSTEPS; ++ks){
        const f32x4 w0 = *(const f32x4*)(bb + dsro + ks*128);
        const f32x4 w1 = *(const f32x4*)(bb + (dsro ^ 16) + ks*128);
        short8 bw;
#pragma unroll
        for (int jj=0;jj<4;jj++){ bw[jj] = f2bf(w0[jj]); bw[jj+4] = f2bf(w1[jj]); }
        accNW   = __builtin_amdgcn_mfma_f32_16x16x32_bf16(bw, bw, accNW, 0, 0, 0);
        accW[0] = __builtin_amdgcn_mfma_f32_16x16x32_bf16(afr[0][ks], bw, accW[0], 0, 0, 0);
        accW[1] = __builtin_amdgcn_mfma_f32_16x16x32_bf16(afr[1][ks], bw, accW[1], 0, 0, 0);
      }
    } else {
      // ---- Q half-tile ----
#pragma unroll
      for (int ks=0; ks<KSTEPS; ++ks){
        const f32x4 z0 = *(const f32x4*)(bb + dsro + ks*128);
        const f32x4 z1 = *(const f32x4*)(bb + (dsro ^ 16) + ks*128);
        short8 bq;
#pragma unroll
        for (int jj=0;jj<4;jj++){ bq[jj] = f2bf(z0[jj]); bq[jj+4] = f2bf(z1[jj]); }
        accNQ   = __builtin_amdgcn_mfma_f32_16x16x32_bf16(bq, bq, accNQ, 0, 0, 0);
        accQ[0] = __builtin_amdgcn_mfma_f32_16x16x32_bf16(afr[0][ks], bq, accQ[0], 0, 0, 0);
        accQ[1] = __builtin_amdgcn_mfma_f32_16x16x32_bf16(afr[1][ks], bq, accQ[1], 0, 0, 0);
      }

      // ---- epilogue for tile k=j>>1 (register-accumulated, zero vmem) ----
      float winv, qinv;
      {
        int rsel = lcol & 3;
        float vw = rsel==0?accNW[0]:rsel==1?accNW[1]:rsel==2?accNW[2]:accNW[3];
        float vq = rsel==0?accNQ[0]:rsel==1?accNQ[1]:rsel==2?accNQ[2]:accNQ[3];
        int src = ((lcol>>2)<<4) | lcol;          // diag col c on lane ((c>>2)<<4)|c
        float ssW = __shfl(vw, src);
        float ssQ = __shfl(vq, src);
        winv = 1.0f / fmaxf(sqrtf(ssW), 1e-5f);
        qinv = 1.0f / fmaxf(sqrtf(ssQ), 1e-12f);
      }
      const int c = (bid + (j>>1)*GRID)*16 + lcol;
#pragma unroll
      for (int rb=0;rb<2;rb++){
#pragma unroll
        for (int r=0;r<4;r++){
          const int lab = labr[rb][r];
          float cw = accW[rb][r] * winv;
          cw = fminf(fmaxf(cw, -1.0f + 1e-7f), 1.0f - 1e-7f);
          float cq = accQ[rb][r] * qinv;
          if (c == lab){
            float sw  = sqrtf(fminf(fmaxf(1.0f - cw*cw, 0.0f), 1.0f));
            posW[rb][r] = __expf(-S_SCALE*(cw*COS_M - sw*SIN_M));
            float vq  = 0.3f * cq;
            float sq  = sqrtf(fminf(fmaxf(1.0f - vq*vq, 0.0f), 1.0f));
            posQ[rb][r] = __expf(-S_SCALE*(vq*COS_M - sq*SIN_M));
          } else {
            nwacc[rb][r] += __expf(S_SCALE*cw);
            nqacc[rb][r] += __expf(S_SCALE*cq);
          }
        }
      }
      accW[0]=vzero; accW[1]=vzero; accQ[0]=vzero; accQ[1]=vzero;
      accNW=vzero; accNQ=vzero;
    }
  }

  // ---- flush: per-row 16-lane reduce + single store pass ----
#pragma unroll
  for (int rb=0;rb<2;rb++){
#pragma unroll
    for (int r=0;r<4;r++){
      float nw = nwacc[rb][r], nq = nqacc[rb][r];
#pragma unroll
      for (int msk=1; msk<16; msk<<=1){
        nw += __shfl_xor(nw, msk);
        nq += __shfl_xor(nq, msk);
      }
      const int m = wave*32 + rb*16 + lkg*4 + r;
      if (lcol == 0){
        partials[(size_t)bid*512 + m]       = nw;
        partials[(size_t)bid*512 + 256 + m] = nq;
      }
      if (posW[rb][r] > -0.5f) posval[m]         = posW[rb][r];
      if (posQ[rb][r] > -0.5f) posval[NROWS + m] = posQ[rb][r];
    }
  }
}

// ---- reduce partials per row over 256 blocks, loss per row ----
__global__ void k_red(const float* __restrict__ partials, const float* __restrict__ posval,
                      float* __restrict__ lossv){
  int n = blockIdx.x, t = threadIdx.x;            // 512 blocks x 256 threads
  float s = partials[(size_t)t*512 + n];
  __shared__ float red[256];
  red[t] = s; __syncthreads();
  for (int o=128;o>0;o>>=1){ if(t<o) red[t]+=red[t+o]; __syncthreads(); }
  if (t==0) lossv[n] = logf(1.0f + red[0] * posval[n]);
}

__global__ void k_fin(const float* __restrict__ lossv, const int* __restrict__ epoch,
                      float* __restrict__ out){
  int t = threadIdx.x;
  int N = (epoch[0] + 1 >= 4) ? 2*NROWS : NROWS;
  float v = (t < N) ? lossv[t] : 0.f;
  __shared__ float red[512];
  red[t] = v; __syncthreads();
  for (int o=256;o>0;o>>=1){ if(t<o) red[t]+=red[t+o]; __syncthreads(); }
  if (t==0) out[0] = red[0] / (float)N;
}

extern "C" void kernel_launch(void* const* d_in, const int* in_sizes, int n_in,
                              void* d_out, int out_size, void* d_ws, size_t ws_size,
                              hipStream_t stream)
{
  const float* x      = (const float*)d_in[0];
  const int*   labels = (const int*)d_in[1];
  const float* W      = (const float*)d_in[2];
  const float* Q      = (const float*)d_in[3];
  const int*   epoch  = (const int*)d_in[4];
  float* out = (float*)d_out;
  const int C      = in_sizes[2] / D_DIM;         // 100000
  const int ntiles = (C + NT - 1) / NT;           // 6250

  char* ws = (char*)d_ws;
  float* emb      = (float*)(ws + 0);             // 512 KB
  short* embA     = (short*)(ws + 524288);        // 256 KB
  float* newrow   = (float*)(ws + 786432);        // 512 KB
  int*   upd      = (int*)  (ws + 1310720);       // 400 KB
  float* posval   = (float*)(ws + 1712128);       // 2 KB
  float* lossv    = (float*)(ws + 1714176);       // 2 KB
  float* partials = (float*)(ws + 1716224);       // 256*512*4 = 512 KB

  hipLaunchKernelGGL(k_emb,  dim3(NROWS),  dim3(256), 0, stream, x, emb, embA, upd, C);
  hipLaunchKernelGGL(k_vp,   dim3(NROWS),  dim3(256), 0, stream, Q, emb, labels, newrow, upd);
  hipLaunchKernelGGL(k_main, dim3(GRID),   dim3(512), 0, stream,
                     W, Q, embA, newrow, upd, labels, partials, posval, C, ntiles);
  hipLaunchKernelGGL(k_red,  dim3(2*NROWS),dim3(256), 0, stream, partials, posval, lossv);
  hipLaunchKernelGGL(k_fin,  dim3(1),      dim3(512), 0, stream, lossv, epoch, out);
}